// Round 5
// baseline (910.007 us; speedup 1.0000x reference)
//
#include <hip/hip_runtime.h>

#define B_   2
#define S_   2048
#define H_   32
#define D_   64
#define HID_ 2048

typedef unsigned short ushort_t;
typedef __attribute__((ext_vector_type(8))) short short8;
typedef __attribute__((ext_vector_type(4))) float floatx4;
typedef __attribute__((ext_vector_type(4))) unsigned short ushort4v;

typedef const __attribute__((address_space(1))) char* gas_ptr;
typedef __attribute__((address_space(3))) char* las_ptr;

__device__ __forceinline__ float bf2f(ushort_t u) {
    union { unsigned int i; float f; } v; v.i = ((unsigned int)u) << 16; return v.f;
}
__device__ __forceinline__ ushort_t f2bf(float f) {
    union { float f; unsigned int i; } v; v.f = f;
    unsigned int x = v.i;
    unsigned int r = x + 0x7fffu + ((x >> 16) & 1u);
    return (ushort_t)(r >> 16);
}

// fp32 -> bf16 cast, 8 elements/thread.
__global__ __launch_bounds__(256) void cast_f32_bf16(const float* __restrict__ in,
                                                     ushort_t* __restrict__ out,
                                                     int n8) {
    int i = blockIdx.x * 256 + threadIdx.x;
    if (i >= n8) return;
    const float4* p = (const float4*)(in + (size_t)i * 8);
    float4 a = p[0], b = p[1];
    short8 o;
    o[0] = (short)f2bf(a.x); o[1] = (short)f2bf(a.y);
    o[2] = (short)f2bf(a.z); o[3] = (short)f2bf(a.w);
    o[4] = (short)f2bf(b.x); o[5] = (short)f2bf(b.y);
    o[6] = (short)f2bf(b.z); o[7] = (short)f2bf(b.w);
    *(short8*)(out + (size_t)i * 8) = o;
}

// Pack int32 bool mask -> bitmask, 1 bit per element. bit i of out[w] = mask[w*64+i].
__global__ __launch_bounds__(256) void mask_pack(const int* __restrict__ m,
                                                 unsigned long long* __restrict__ bits) {
    int idx = blockIdx.x * 256 + threadIdx.x;
    unsigned long long bal = __ballot(m[idx] != 0);
    if ((threadIdx.x & 63) == 0) bits[idx >> 6] = bal;
}

// C = A @ B^T.  A: M x K bf16 row-major, B: N x K bf16 row-major.
// 128x128 tile, BK=32, global_load_lds width-16 staging, XOR-swizzled flat LDS.
template <bool OF32>
__global__ __launch_bounds__(256) void gemm_bt(const ushort_t* __restrict__ A,
                                               const ushort_t* __restrict__ Bm,
                                               void* __restrict__ Cv,
                                               int M, int N, int K) {
    __shared__ ushort_t lA[128 * 32];
    __shared__ ushort_t lB[128 * 32];
    const int tid  = threadIdx.x;
    const int lane = tid & 63, wave = tid >> 6;
    const int quad = lane >> 4, l16 = lane & 15;
    const int wm = wave >> 1, wn = wave & 1;
    const int m0 = blockIdx.y * 128, n0 = blockIdx.x * 128;

    const int srow = tid >> 2;
    const int gseg = (tid & 3) ^ ((tid >> 3) & 3);
    const ushort_t* gA = A + (size_t)(m0 + srow) * K + gseg * 8;
    const ushort_t* gB = Bm + (size_t)(n0 + srow) * K + gseg * 8;

    const int fseg = quad ^ ((l16 >> 1) & 3);

    floatx4 acc[4][4];
#pragma unroll
    for (int i = 0; i < 4; i++)
#pragma unroll
        for (int j = 0; j < 4; j++) acc[i][j] = (floatx4){0.f, 0.f, 0.f, 0.f};

    for (int k0 = 0; k0 < K; k0 += 32) {
#pragma unroll
        for (int j = 0; j < 2; j++) {
            __builtin_amdgcn_global_load_lds(
                (gas_ptr)(gA + (size_t)j * 64 * K + k0),
                (las_ptr)(lA + j * 2048 + wave * 512), 16, 0, 0);
            __builtin_amdgcn_global_load_lds(
                (gas_ptr)(gB + (size_t)j * 64 * K + k0),
                (las_ptr)(lB + j * 2048 + wave * 512), 16, 0, 0);
        }
        __syncthreads();

        short8 aF[4], bF[4];
#pragma unroll
        for (int mi = 0; mi < 4; mi++)
            aF[mi] = *(const short8*)&lA[(wm * 64 + mi * 16 + l16) * 32 + fseg * 8];
#pragma unroll
        for (int ni = 0; ni < 4; ni++)
            bF[ni] = *(const short8*)&lB[(wn * 64 + ni * 16 + l16) * 32 + fseg * 8];
#pragma unroll
        for (int mi = 0; mi < 4; mi++)
#pragma unroll
            for (int ni = 0; ni < 4; ni++)
                acc[mi][ni] = __builtin_amdgcn_mfma_f32_16x16x32_bf16(aF[mi], bF[ni], acc[mi][ni], 0, 0, 0);
        __syncthreads();
    }

#pragma unroll
    for (int mi = 0; mi < 4; mi++)
#pragma unroll
        for (int ni = 0; ni < 4; ni++)
#pragma unroll
            for (int r = 0; r < 4; r++) {
                int row = m0 + wm * 64 + mi * 16 + quad * 4 + r;
                int col = n0 + wn * 64 + ni * 16 + l16;
                if (OF32) ((float*)Cv)[(size_t)row * N + col] = acc[mi][ni][r];
                else      ((ushort_t*)Cv)[(size_t)row * N + col] = f2bf(acc[mi][ni][r]);
            }
}

// qkv: (B,S,H,3D) bf16 -> q_rot (pre-scaled by 1/8), k_rot as (B,H,S,D) bf16.
__global__ __launch_bounds__(256) void rope_qk(const ushort_t* __restrict__ qkv,
                                               const int* __restrict__ pos,
                                               ushort_t* __restrict__ qr,
                                               ushort_t* __restrict__ kr) {
    int idx = blockIdx.x * 256 + threadIdx.x;   // (b,h,s,d): d fastest
    int d = idx & 63;
    int s = (idx >> 6) & 2047;
    int h = (idx >> 17) & 31;
    int b = idx >> 22;
    size_t qbase = ((size_t)(b * S_ + s)) * (3 * H_ * D_) + h * (3 * D_);
    int i  = d & 31;
    int d2 = d ^ 32;
    float x   = bf2f(qkv[qbase + d]);
    float xp  = bf2f(qkv[qbase + d2]);
    float kx  = bf2f(qkv[qbase + 64 + d]);
    float kxp = bf2f(qkv[qbase + 64 + d2]);
    int   p   = pos[b * S_ + s];
    float inv = 1.0f / powf(10000.0f, (float)(2 * i) / 64.0f);
    float t   = (float)p * inv;
    float c = cosf(t), sn = sinf(t);
    float rq = (d < 32) ? -xp : xp;
    float rk = (d < 32) ? -kxp : kxp;
    float qo = (x * c + rq * sn) * 0.125f;   // fold 1/sqrt(D) into q
    float ko = kx * c + rk * sn;
    size_t o = ((size_t)(b * H_ + h) * S_ + s) * D_ + d;
    qr[o] = f2bf(qo);
    kr[o] = f2bf(ko);
}

// v transpose: qkv (B,S,H,3D) -> vt (B,H,D,S).
__global__ __launch_bounds__(256) void v_trans(const ushort_t* __restrict__ qkv,
                                               ushort_t* __restrict__ vt) {
    int idx = blockIdx.x * 256 + threadIdx.x;   // (b,h,d,s): s fastest
    int s = idx & 2047;
    int d = (idx >> 11) & 63;
    int h = (idx >> 17) & 31;
    int b = idx >> 22;
    vt[idx] = qkv[((size_t)(b * S_ + s)) * (3 * H_ * D_) + h * (3 * D_) + 128 + d];
}

// Flash attention, transposed-score + fixed-max softmax + K reg-prefetch.
// Grid: flat 2048 blocks; swizzled so each XCD owns 8 head-instances (K/V fits its L2).
__global__ __launch_bounds__(256) void attn_kernel(const ushort_t* __restrict__ qr,
                                                   const ushort_t* __restrict__ kr,
                                                   const ushort_t* __restrict__ vt,
                                                   const unsigned long long* __restrict__ mbits,
                                                   ushort_t* __restrict__ ctx) {
    __shared__ ushort_t lds_p[4][16][72];   // per-wave P tile [q=16][k=64 (+8 pad)]
    const int tid  = threadIdx.x;
    const int wave = tid >> 6, lane = tid & 63;
    const int quad = lane >> 4, l16 = lane & 15;

    // XCD head-clustering: id%8 selects XCD (round-robin); keep head-instance g fixed per XCD.
    const int id   = blockIdx.x;
    const int g    = (id & 7) | ((id >> 8) << 3);   // head-instance 0..63 (= b*32+h)
    const int qblk = (id >> 3) & 31;
    const int b    = g >> 5;
    const int q0   = qblk * 64 + wave * 16;
    const size_t headBase = (size_t)g * S_ * D_;
    const unsigned long long* mrow = mbits + ((size_t)b * S_ + q0 + l16) * (S_ / 64);

    const ushort_t* krL = kr + headBase + (size_t)l16 * D_ + quad * 8;
    const ushort_t* vtL = vt + headBase + (size_t)l16 * S_ + quad * 8;

    // Q as B-operand (pre-scaled by 1/8 at rope)
    short8 qf0 = *(const short8*)(qr + headBase + (size_t)(q0 + l16) * D_ + quad * 8);
    short8 qf1 = *(const short8*)(qr + headBase + (size_t)(q0 + l16) * D_ + 32 + quad * 8);

    float l_st = 0.f;
    floatx4 o[4];
#pragma unroll
    for (int t = 0; t < 4; t++) o[t] = (floatx4){0.f, 0.f, 0.f, 0.f};

    auto loadK = [&](short8 (&kf)[4][2], int kk) {
#pragma unroll
        for (int t = 0; t < 4; t++) {
            const ushort_t* kp = krL + (size_t)(kk + t * 16) * D_;
            kf[t][0] = *(const short8*)(kp);
            kf[t][1] = *(const short8*)(kp + 32);
        }
    };

    auto body = [&](short8 (&kf)[4][2], unsigned long long mb, int k0) {
        // QK^T (transposed: rows = k-local, col = q = l16)
        floatx4 scT[4];
#pragma unroll
        for (int t = 0; t < 4; t++) scT[t] = (floatx4){0.f, 0.f, 0.f, 0.f};
#pragma unroll
        for (int t = 0; t < 4; t++) {
            scT[t] = __builtin_amdgcn_mfma_f32_16x16x32_bf16(kf[t][0], qf0, scT[t], 0, 0, 0);
            scT[t] = __builtin_amdgcn_mfma_f32_16x16x32_bf16(kf[t][1], qf1, scT[t], 0, 0, 0);
        }

        // V loads early: ~350 cyc of slack (softmax + LDS round trip) before first use
        short8 vf[4][2];
#pragma unroll
        for (int t = 0; t < 4; t++) {
            const ushort_t* vp = vtL + (size_t)(t * 16) * S_ + k0;
            vf[t][0] = *(const short8*)(vp);
            vf[t][1] = *(const short8*)(vp + 32);
        }

        // fixed-max softmax numerator: exp(s), zero where masked; no cross-lane ops
        float pv[4][4];
        float rs = 0.f;
#pragma unroll
        for (int t = 0; t < 4; t++)
#pragma unroll
            for (int r = 0; r < 4; r++) {
                int kl = t * 16 + quad * 4 + r;
                float e = __expf(scT[t][r]);
                e = ((mb >> kl) & 1ull) ? 0.f : e;
                pv[t][r] = e;
                rs += e;
            }
        l_st += rs;   // lane-partial; reduced across quads once at the end

        // P row q=l16: per t, 4 contiguous k-slots -> one b64 write (2-way, free)
#pragma unroll
        for (int t = 0; t < 4; t++) {
            ushort4v w;
            w[0] = f2bf(pv[t][0]); w[1] = f2bf(pv[t][1]);
            w[2] = f2bf(pv[t][2]); w[3] = f2bf(pv[t][3]);
            *(ushort4v*)&lds_p[wave][l16][t * 16 + quad * 4] = w;
        }
        // P as A-operand: A[m=q(l16)][k]
        short8 pf0 = *(const short8*)&lds_p[wave][l16][quad * 8];
        short8 pf1 = *(const short8*)&lds_p[wave][l16][32 + quad * 8];

#pragma unroll
        for (int t = 0; t < 4; t++) {
            o[t] = __builtin_amdgcn_mfma_f32_16x16x32_bf16(pf0, vf[t][0], o[t], 0, 0, 0);
            o[t] = __builtin_amdgcn_mfma_f32_16x16x32_bf16(pf1, vf[t][1], o[t], 0, 0, 0);
        }
    };

    // ping-pong: prefetch next K tile while computing current
    short8 kA[4][2], kB[4][2];
    loadK(kA, 0);
    unsigned long long mbA = mrow[0], mbB;
    for (int k0 = 0; k0 < S_; k0 += 128) {
        mbB = mrow[(k0 >> 6) + 1];
        loadK(kB, k0 + 64);
        body(kA, mbA, k0);
        int kn = (k0 + 128 < S_) ? (k0 + 128) : 0;   // clamped dummy reload on last iter
        mbA = mrow[kn >> 6];
        loadK(kA, kn);
        body(kB, mbB, k0 + 64);
    }

    // single end-of-kernel l reduction
    l_st += __shfl_xor(l_st, 16);
    l_st += __shfl_xor(l_st, 32);
    float li[4];
#pragma unroll
    for (int r = 0; r < 4; r++) li[r] = 1.0f / __shfl(l_st, quad * 4 + r, 16);
#pragma unroll
    for (int t = 0; t < 4; t++)
#pragma unroll
        for (int r = 0; r < 4; r++) {
            int srow = q0 + quad * 4 + r;
            ctx[((size_t)(b * S_) + srow) * (H_ * D_) + (g & 31) * D_ + t * 16 + l16] = f2bf(o[t][r] * li[r]);
        }
}

extern "C" void kernel_launch(void* const* d_in, const int* in_sizes, int n_in,
                              void* d_out, int out_size, void* d_ws, size_t ws_size,
                              hipStream_t stream) {
    const float* hidden          = (const float*)d_in[0];      // fp32 (B,S,HID)
    const int* mask              = (const int*)d_in[1];        // bool -> int32
    const int* pos               = (const int*)d_in[2];        // int32
    const float* Wqkv            = (const float*)d_in[3];      // fp32 (3HD, HID)
    const float* Wo              = (const float*)d_in[4];      // fp32 (HID, HD)
    float* out                   = (float*)d_out;              // fp32 (B,S,HID)

    char* ws = (char*)d_ws;
    ushort_t* qkv     = (ushort_t*)(ws);
    ushort_t* ctx     = (ushort_t*)(ws);
    unsigned long long* mbits = (unsigned long long*)(ws + 16777216);
    ushort_t* Wo_bf   = (ushort_t*)(ws + 50331648);
    ushort_t* hid_bf  = (ushort_t*)(ws + 58720256);
    ushort_t* Wqkv_bf = (ushort_t*)(ws + 75497472);
    ushort_t* q_r     = (ushort_t*)(ws + 58720256);
    ushort_t* k_r     = (ushort_t*)(ws + 75497472);
    ushort_t* v_t     = (ushort_t*)(ws + 92274688);

    // 0. casts fp32 -> bf16
    {
        int n8 = (B_ * S_ * HID_) / 8;
        cast_f32_bf16<<<n8 / 256, 256, 0, stream>>>(hidden, hid_bf, n8);
        n8 = (3 * H_ * D_ * HID_) / 8;
        cast_f32_bf16<<<n8 / 256, 256, 0, stream>>>(Wqkv, Wqkv_bf, n8);
        n8 = (HID_ * H_ * D_) / 8;
        cast_f32_bf16<<<n8 / 256, 256, 0, stream>>>(Wo, Wo_bf, n8);
    }

    // 1. QKV projection: (B*S, HID) @ W_qkv^T -> (B*S, 3*H*D) bf16
    gemm_bt<false><<<dim3((3 * H_ * D_) / 128, (B_ * S_) / 128), 256, 0, stream>>>(
        hid_bf, Wqkv_bf, qkv, B_ * S_, 3 * H_ * D_, HID_);

    // 2. RoPE (q,k) + v transpose
    int nElem = B_ * H_ * S_ * D_;
    rope_qk<<<nElem / 256, 256, 0, stream>>>(qkv, pos, q_r, k_r);
    v_trans<<<nElem / 256, 256, 0, stream>>>(qkv, v_t);

    // 2b. pack mask bits (qkv region now dead)
    mask_pack<<<(B_ * S_ * S_) / 256, 256, 0, stream>>>(mask, mbits);

    // 3. Flash attention -> ctx (B,S,H*D) bf16
    attn_kernel<<<2048, 256, 0, stream>>>(q_r, k_r, v_t, mbits, ctx);

    // 4. Output projection: (B*S, H*D) @ W_o^T -> (B*S, HID) fp32
    gemm_bt<true><<<dim3(HID_ / 128, (B_ * S_) / 128), 256, 0, stream>>>(
        ctx, Wo_bf, out, B_ * S_, HID_, H_ * D_);
}

// Round 6
// 577.260 us; speedup vs baseline: 1.5764x; 1.5764x over previous
//
#include <hip/hip_runtime.h>

#define B_   2
#define S_   2048
#define H_   32
#define D_   64
#define HID_ 2048

typedef unsigned short ushort_t;
typedef __attribute__((ext_vector_type(8))) short short8;
typedef __attribute__((ext_vector_type(4))) float floatx4;
typedef __attribute__((ext_vector_type(4))) unsigned short ushort4v;

typedef const __attribute__((address_space(1))) char* gas_ptr;
typedef __attribute__((address_space(3))) char* las_ptr;

__device__ __forceinline__ float bf2f(ushort_t u) {
    union { unsigned int i; float f; } v; v.i = ((unsigned int)u) << 16; return v.f;
}
__device__ __forceinline__ ushort_t f2bf(float f) {
    union { float f; unsigned int i; } v; v.f = f;
    unsigned int x = v.i;
    unsigned int r = x + 0x7fffu + ((x >> 16) & 1u);
    return (ushort_t)(r >> 16);
}

// fp32 -> bf16 cast, 8 elements/thread.
__global__ __launch_bounds__(256) void cast_f32_bf16(const float* __restrict__ in,
                                                     ushort_t* __restrict__ out,
                                                     int n8) {
    int i = blockIdx.x * 256 + threadIdx.x;
    if (i >= n8) return;
    const float4* p = (const float4*)(in + (size_t)i * 8);
    float4 a = p[0], b = p[1];
    short8 o;
    o[0] = (short)f2bf(a.x); o[1] = (short)f2bf(a.y);
    o[2] = (short)f2bf(a.z); o[3] = (short)f2bf(a.w);
    o[4] = (short)f2bf(b.x); o[5] = (short)f2bf(b.y);
    o[6] = (short)f2bf(b.z); o[7] = (short)f2bf(b.w);
    *(short8*)(out + (size_t)i * 8) = o;
}

// Pack int32 bool mask -> bitmask, 1 bit per element.
__global__ __launch_bounds__(256) void mask_pack(const int* __restrict__ m,
                                                 unsigned long long* __restrict__ bits) {
    int idx = blockIdx.x * 256 + threadIdx.x;
    unsigned long long bal = __ballot(m[idx] != 0);
    if ((threadIdx.x & 63) == 0) bits[idx >> 6] = bal;
}

// C = A @ B^T.  (m97-style; unchanged from R5.)
template <bool OF32>
__global__ __launch_bounds__(256) void gemm_bt(const ushort_t* __restrict__ A,
                                               const ushort_t* __restrict__ Bm,
                                               void* __restrict__ Cv,
                                               int M, int N, int K) {
    __shared__ ushort_t lA[128 * 32];
    __shared__ ushort_t lB[128 * 32];
    const int tid  = threadIdx.x;
    const int lane = tid & 63, wave = tid >> 6;
    const int quad = lane >> 4, l16 = lane & 15;
    const int wm = wave >> 1, wn = wave & 1;
    const int m0 = blockIdx.y * 128, n0 = blockIdx.x * 128;

    const int srow = tid >> 2;
    const int gseg = (tid & 3) ^ ((tid >> 3) & 3);
    const ushort_t* gA = A + (size_t)(m0 + srow) * K + gseg * 8;
    const ushort_t* gB = Bm + (size_t)(n0 + srow) * K + gseg * 8;

    const int fseg = quad ^ ((l16 >> 1) & 3);

    floatx4 acc[4][4];
#pragma unroll
    for (int i = 0; i < 4; i++)
#pragma unroll
        for (int j = 0; j < 4; j++) acc[i][j] = (floatx4){0.f, 0.f, 0.f, 0.f};

    for (int k0 = 0; k0 < K; k0 += 32) {
#pragma unroll
        for (int j = 0; j < 2; j++) {
            __builtin_amdgcn_global_load_lds(
                (gas_ptr)(gA + (size_t)j * 64 * K + k0),
                (las_ptr)(lA + j * 2048 + wave * 512), 16, 0, 0);
            __builtin_amdgcn_global_load_lds(
                (gas_ptr)(gB + (size_t)j * 64 * K + k0),
                (las_ptr)(lB + j * 2048 + wave * 512), 16, 0, 0);
        }
        __syncthreads();

        short8 aF[4], bF[4];
#pragma unroll
        for (int mi = 0; mi < 4; mi++)
            aF[mi] = *(const short8*)&lA[(wm * 64 + mi * 16 + l16) * 32 + fseg * 8];
#pragma unroll
        for (int ni = 0; ni < 4; ni++)
            bF[ni] = *(const short8*)&lB[(wn * 64 + ni * 16 + l16) * 32 + fseg * 8];
#pragma unroll
        for (int mi = 0; mi < 4; mi++)
#pragma unroll
            for (int ni = 0; ni < 4; ni++)
                acc[mi][ni] = __builtin_amdgcn_mfma_f32_16x16x32_bf16(aF[mi], bF[ni], acc[mi][ni], 0, 0, 0);
        __syncthreads();
    }

#pragma unroll
    for (int mi = 0; mi < 4; mi++)
#pragma unroll
        for (int ni = 0; ni < 4; ni++)
#pragma unroll
            for (int r = 0; r < 4; r++) {
                int row = m0 + wm * 64 + mi * 16 + quad * 4 + r;
                int col = n0 + wn * 64 + ni * 16 + l16;
                if (OF32) ((float*)Cv)[(size_t)row * N + col] = acc[mi][ni][r];
                else      ((ushort_t*)Cv)[(size_t)row * N + col] = f2bf(acc[mi][ni][r]);
            }
}

// qkv: (B,S,H,3D) bf16 -> q_rot (pre-scaled by 1/8), k_rot as (B,H,S,D) bf16.
__global__ __launch_bounds__(256) void rope_qk(const ushort_t* __restrict__ qkv,
                                               const int* __restrict__ pos,
                                               ushort_t* __restrict__ qr,
                                               ushort_t* __restrict__ kr) {
    int idx = blockIdx.x * 256 + threadIdx.x;   // (b,h,s,d): d fastest
    int d = idx & 63;
    int s = (idx >> 6) & 2047;
    int h = (idx >> 17) & 31;
    int b = idx >> 22;
    size_t qbase = ((size_t)(b * S_ + s)) * (3 * H_ * D_) + h * (3 * D_);
    int i  = d & 31;
    int d2 = d ^ 32;
    float x   = bf2f(qkv[qbase + d]);
    float xp  = bf2f(qkv[qbase + d2]);
    float kx  = bf2f(qkv[qbase + 64 + d]);
    float kxp = bf2f(qkv[qbase + 64 + d2]);
    int   p   = pos[b * S_ + s];
    float inv = 1.0f / powf(10000.0f, (float)(2 * i) / 64.0f);
    float t   = (float)p * inv;
    float c = cosf(t), sn = sinf(t);
    float rq = (d < 32) ? -xp : xp;
    float rk = (d < 32) ? -kxp : kxp;
    float qo = (x * c + rq * sn) * 0.125f;
    float ko = kx * c + rk * sn;
    size_t o = ((size_t)(b * H_ + h) * S_ + s) * D_ + d;
    qr[o] = f2bf(qo);
    kr[o] = f2bf(ko);
}

// v transpose: qkv (B,S,H,3D) -> vt (B,H,D,S).
__global__ __launch_bounds__(256) void v_trans(const ushort_t* __restrict__ qkv,
                                               ushort_t* __restrict__ vt) {
    int idx = blockIdx.x * 256 + threadIdx.x;   // (b,h,d,s): s fastest
    int s = idx & 2047;
    int d = (idx >> 11) & 63;
    int h = (idx >> 17) & 31;
    int b = idx >> 22;
    vt[idx] = qkv[((size_t)(b * S_ + s)) * (3 * H_ * D_) + h * (3 * D_) + 128 + d];
}

// Flash attention v3: block-cooperative LDS staging of K/V tiles (global_load_lds,
// XOR-swizzled segs), transposed scores, fixed-reference softmax, bitmask.
// Block = 4 waves = 64 q-rows of one head-instance. Grid 2048, XCD-clustered.
__global__ __launch_bounds__(256) void attn_kernel(const ushort_t* __restrict__ qr,
                                                   const ushort_t* __restrict__ kr,
                                                   const ushort_t* __restrict__ vt,
                                                   const unsigned long long* __restrict__ mbits,
                                                   ushort_t* __restrict__ ctx) {
    __shared__ ushort_t lK[64 * 64];        // [k-local][d], segs XOR-swizzled by row&7
    __shared__ ushort_t lV[64 * 64];        // [d][k-local], same swizzle
    __shared__ ushort_t lds_p[4][16][72];   // per-wave P tile
    const int tid  = threadIdx.x;
    const int wave = tid >> 6, lane = tid & 63;
    const int quad = lane >> 4, l16 = lane & 15;

    const int id   = blockIdx.x;
    const int g    = (id & 7) | ((id >> 8) << 3);   // head-instance, 8 per XCD
    const int qblk = (id >> 3) & 31;
    const int b    = g >> 5;
    const int q0   = qblk * 64 + wave * 16;
    const size_t headBase = (size_t)g * S_ * D_;
    const unsigned long long* mrow = mbits + ((size_t)b * S_ + q0 + l16) * (S_ / 64);

    // staging: lane covers row sr (of 8), seg ss; global seg = ss ^ (row&7) = ss ^ sr
    const int sr = lane >> 3, ss = lane & 7;
    const int gss = ss ^ sr;
    const ushort_t* gK0 = kr + headBase + (size_t)(wave * 16 + sr) * D_ + gss * 8;
    const ushort_t* gV0 = vt + headBase + (size_t)(wave * 16 + sr) * S_ + gss * 8;

    // fragment read segs (element offsets): seg q ^ (row&7), row&7 = l16&7
    const int segA0 = ((quad)     ^ (l16 & 7)) * 8;
    const int segA1 = ((quad + 4) ^ (l16 & 7)) * 8;
    const int rowOff = (l16)*64;   // within 16-row group, * 64 elem/row

    // Q as B-operand (pre-scaled by 1/8 at rope)
    short8 qf0 = *(const short8*)(qr + headBase + (size_t)(q0 + l16) * D_ + quad * 8);
    short8 qf1 = *(const short8*)(qr + headBase + (size_t)(q0 + l16) * D_ + 32 + quad * 8);

    float l_st = 0.f;
    floatx4 o[4];
#pragma unroll
    for (int t = 0; t < 4; t++) o[t] = (floatx4){0.f, 0.f, 0.f, 0.f};

    for (int k0 = 0; k0 < S_; k0 += 64) {
        // cooperative staging: 4 instrs/wave, 16/block, each 1 KB coalesced
#pragma unroll
        for (int i = 0; i < 2; i++) {
            __builtin_amdgcn_global_load_lds(
                (gas_ptr)(gK0 + (size_t)(k0 + i * 8) * D_),
                (las_ptr)(lK + (wave * 16 + i * 8) * 64), 16, 0, 0);
            __builtin_amdgcn_global_load_lds(
                (gas_ptr)(gV0 + (size_t)(i * 8) * S_ + k0),
                (las_ptr)(lV + (wave * 16 + i * 8) * 64), 16, 0, 0);
        }
        unsigned long long mb = mrow[k0 >> 6];
        __syncthreads();

        // QK^T transposed: scT rows = k-local, col = q (l16); K as A-operand from LDS
        floatx4 scT[4];
#pragma unroll
        for (int t = 0; t < 4; t++) scT[t] = (floatx4){0.f, 0.f, 0.f, 0.f};
#pragma unroll
        for (int t = 0; t < 4; t++) {
            short8 kf0 = *(const short8*)&lK[t * 1024 + rowOff + segA0];
            short8 kf1 = *(const short8*)&lK[t * 1024 + rowOff + segA1];
            scT[t] = __builtin_amdgcn_mfma_f32_16x16x32_bf16(kf0, qf0, scT[t], 0, 0, 0);
            scT[t] = __builtin_amdgcn_mfma_f32_16x16x32_bf16(kf1, qf1, scT[t], 0, 0, 0);
        }

        // fixed-reference softmax numerator; masked -> 0
        float pv[4][4];
        float rs = 0.f;
#pragma unroll
        for (int t = 0; t < 4; t++)
#pragma unroll
            for (int r = 0; r < 4; r++) {
                int kl = t * 16 + quad * 4 + r;
                float e = __expf(scT[t][r]);
                e = ((mb >> kl) & 1ull) ? 0.f : e;
                pv[t][r] = e;
                rs += e;
            }
        l_st += rs;

        // P row q=l16 -> per-wave LDS (C-layout -> A-layout)
#pragma unroll
        for (int t = 0; t < 4; t++) {
            ushort4v w;
            w[0] = f2bf(pv[t][0]); w[1] = f2bf(pv[t][1]);
            w[2] = f2bf(pv[t][2]); w[3] = f2bf(pv[t][3]);
            *(ushort4v*)&lds_p[wave][l16][t * 16 + quad * 4] = w;
        }
        short8 pf0 = *(const short8*)&lds_p[wave][l16][quad * 8];
        short8 pf1 = *(const short8*)&lds_p[wave][l16][32 + quad * 8];

        // PV: V as B-operand from LDS
#pragma unroll
        for (int t = 0; t < 4; t++) {
            short8 vf0 = *(const short8*)&lV[t * 1024 + rowOff + segA0];
            short8 vf1 = *(const short8*)&lV[t * 1024 + rowOff + segA1];
            o[t] = __builtin_amdgcn_mfma_f32_16x16x32_bf16(pf0, vf0, o[t], 0, 0, 0);
            o[t] = __builtin_amdgcn_mfma_f32_16x16x32_bf16(pf1, vf1, o[t], 0, 0, 0);
        }
        __syncthreads();
    }

    // single end-of-kernel l reduction
    l_st += __shfl_xor(l_st, 16);
    l_st += __shfl_xor(l_st, 32);
    float li[4];
#pragma unroll
    for (int r = 0; r < 4; r++) li[r] = 1.0f / __shfl(l_st, quad * 4 + r, 16);
#pragma unroll
    for (int t = 0; t < 4; t++)
#pragma unroll
        for (int r = 0; r < 4; r++) {
            int srow = q0 + quad * 4 + r;
            ctx[((size_t)(b * S_) + srow) * (H_ * D_) + (g & 31) * D_ + t * 16 + l16] = f2bf(o[t][r] * li[r]);
        }
}

extern "C" void kernel_launch(void* const* d_in, const int* in_sizes, int n_in,
                              void* d_out, int out_size, void* d_ws, size_t ws_size,
                              hipStream_t stream) {
    const float* hidden          = (const float*)d_in[0];
    const int* mask              = (const int*)d_in[1];
    const int* pos               = (const int*)d_in[2];
    const float* Wqkv            = (const float*)d_in[3];
    const float* Wo              = (const float*)d_in[4];
    float* out                   = (float*)d_out;

    char* ws = (char*)d_ws;
    ushort_t* qkv     = (ushort_t*)(ws);
    ushort_t* ctx     = (ushort_t*)(ws);
    unsigned long long* mbits = (unsigned long long*)(ws + 16777216);
    ushort_t* Wo_bf   = (ushort_t*)(ws + 50331648);
    ushort_t* hid_bf  = (ushort_t*)(ws + 58720256);
    ushort_t* Wqkv_bf = (ushort_t*)(ws + 75497472);
    ushort_t* q_r     = (ushort_t*)(ws + 58720256);
    ushort_t* k_r     = (ushort_t*)(ws + 75497472);
    ushort_t* v_t     = (ushort_t*)(ws + 92274688);

    // 0. casts fp32 -> bf16
    {
        int n8 = (B_ * S_ * HID_) / 8;
        cast_f32_bf16<<<n8 / 256, 256, 0, stream>>>(hidden, hid_bf, n8);
        n8 = (3 * H_ * D_ * HID_) / 8;
        cast_f32_bf16<<<n8 / 256, 256, 0, stream>>>(Wqkv, Wqkv_bf, n8);
        n8 = (HID_ * H_ * D_) / 8;
        cast_f32_bf16<<<n8 / 256, 256, 0, stream>>>(Wo, Wo_bf, n8);
    }

    // 1. QKV projection
    gemm_bt<false><<<dim3((3 * H_ * D_) / 128, (B_ * S_) / 128), 256, 0, stream>>>(
        hid_bf, Wqkv_bf, qkv, B_ * S_, 3 * H_ * D_, HID_);

    // 2. RoPE (q,k) + v transpose
    int nElem = B_ * H_ * S_ * D_;
    rope_qk<<<nElem / 256, 256, 0, stream>>>(qkv, pos, q_r, k_r);
    v_trans<<<nElem / 256, 256, 0, stream>>>(qkv, v_t);

    // 2b. pack mask bits
    mask_pack<<<(B_ * S_ * S_) / 256, 256, 0, stream>>>(mask, mbits);

    // 3. Flash attention
    attn_kernel<<<2048, 256, 0, stream>>>(q_r, k_r, v_t, mbits, ctx);

    // 4. Output projection
    gemm_bt<true><<<dim3(HID_ / 128, (B_ * S_) / 128), 256, 0, stream>>>(
        ctx, Wo_bf, out, B_ * S_, HID_, H_ * D_);
}